// Round 10
// baseline (70.279 us; speedup 1.0000x reference)
//
#include <hip/hip_runtime.h>
#include <math.h>

// DecoderGATLayer — 3 flat kernels. f32. S=192, B=2, E=512, H=2, D=256, BH=4.
// Dead inputs: ex_entity, ex_relation, Wxe, Wxr (reference deletes `we`).
// score[bh,t,s] = A[s&3][i] + B[t&3][s] + C[s&3][i] - C[s&3][j] + ba,
//   i = bh*48 + (t>>2), j = (t&3)*48 + (s>>2)
// q/k projections folded into tables via u = W^T wa_slice (verified r7).
// K1: transpose Wv,We -> WTV,WTE.   K2: v,e projections + all score tables.
// K3: attention (softmax+PV) + output fc via direct-Wo wave-dot GEMV.

#define SS 192
// ws float offsets
#define VO  0          // [384][256], row = s*2+b
#define EO  98304
#define TO  196608     // 12*192
#define WTV 198912     // 131072 floats
#define WTE 330240     // (gap fine)
// end ~461312 floats = 1.8 MB

__device__ __forceinline__ float wave_reduce_add(float p) {
    #pragma unroll
    for (int off = 32; off >= 1; off >>= 1) p += __shfl_xor(p, off, 64);
    return p;
}

// ===== K1: transposes. 64 blocks x 1024. WT4[k4*256 + d] = W4[d*128 + k4].
__global__ __launch_bounds__(1024) void k_trans(
    const float* __restrict__ Wv, const float* __restrict__ We,
    float* __restrict__ ws)
{
    int o = blockIdx.x * 1024 + threadIdx.x;   // 0..65535
    const float4* src; float4* dst; int idx;
    if (o < 32768) { src = (const float4*)Wv; dst = (float4*)(ws + WTV); idx = o; }
    else           { src = (const float4*)We; dst = (float4*)(ws + WTE); idx = o - 32768; }
    int d  = idx >> 7;
    int k4 = idx & 127;
    dst[k4 * 256 + d] = src[idx];              // coalesced read, scattered write
}

// ===== K2: blocks 0..191 proj (v,e; split-k x4); 192..199 A/B tables; 200..203 C tables.
__global__ __launch_bounds__(1024) void k_projtab(
    const float* __restrict__ query, const float* __restrict__ entity,
    const float* __restrict__ Wq, const float* __restrict__ bq,
    const float* __restrict__ Wk, const float* __restrict__ bk,
    const float* __restrict__ bv, const float* __restrict__ We,
    const float* __restrict__ be, const float* __restrict__ Wa,
    float* __restrict__ ws)
{
    __shared__ __align__(16) float shbuf[8192];   // proj: partials; tables: red
    __shared__ __align__(16) float uo[516];
    int blk = blockIdx.x;
    int tid = threadIdx.x;
    int wv   = __builtin_amdgcn_readfirstlane(tid >> 6);
    int lane = tid & 63;

    if (blk < 192) {
        // ---- v,e projections: 4 rows/block, split-k x4 (verified r8/r9 body)
        int m  = blk / 96;                     // 0: v(query), 1: e(entity)
        int r0 = (blk % 96) * 4;
        int chunk = __builtin_amdgcn_readfirstlane(tid >> 8);
        int d  = tid & 255;
        const float*  A    = m ? entity : query;
        const float*  bias = m ? be : bv;
        const float4* WT   = (const float4*)(ws + (m ? WTE : WTV));
        float*        dst  = ws + (m ? EO : VO);
        const float4* A4   = (const float4*)A;   // [384][128]

        float acc[4];
        #pragma unroll
        for (int r = 0; r < 4; r++) acc[r] = 0.f;

        int k4b = chunk * 32;
        #pragma unroll 8
        for (int i = 0; i < 32; i++) {
            int k4 = k4b + i;
            float4 w = WT[k4 * 256 + d];
            #pragma unroll
            for (int r = 0; r < 4; r++) {
                float4 a = A4[(r0 + r) * 128 + k4];   // wave-uniform -> s_load
                acc[r] += a.x * w.x + a.y * w.y + a.z * w.z + a.w * w.w;
            }
        }
        #pragma unroll
        for (int r = 0; r < 4; r++) shbuf[(chunk * 4 + r) * 256 + d] = acc[r];
        __syncthreads();
        {
            int idx = tid;                     // r*256 + d
            int rr  = idx >> 8, dd = idx & 255;
            float v = shbuf[idx] + shbuf[1024 + idx] + shbuf[2048 + idx] + shbuf[3072 + idx];
            dst[(size_t)(r0 + rr) * 256 + dd] = v + bias[dd];
        }
        return;
    }

    if (blk < 200) {
        // ---- A/B tables via u = W^T wa_slice (verified r7 body)
        float* red = shbuf;                    // [16][512]
        int tab = blk - 192;                   // 0..7
        int p   = (tab < 4) ? tab : tab - 4;
        int b   = p >> 1, h = p & 1;
        const float* wa   = Wa + ((tab < 4) ? 0 : 256);
        const float* W    = h ? We : ((tab < 4) ? Wq : Wk);
        const float* bias = h ? be : ((tab < 4) ? bq : bk);
        const float* x    = h ? entity : query;

        float u8[8];
        #pragma unroll
        for (int i = 0; i < 8; i++) u8[i] = 0.f;
        #pragma unroll 4
        for (int dd = 0; dd < 16; dd++) {
            int d = wv * 16 + dd;
            float wad = wa[d];                                  // wave-uniform
            const float4* Wr = (const float4*)(W + (size_t)d * 512);
            float4 w0 = Wr[lane * 2], w1 = Wr[lane * 2 + 1];    // coalesced
            u8[0] += wad * w0.x; u8[1] += wad * w0.y; u8[2] += wad * w0.z; u8[3] += wad * w0.w;
            u8[4] += wad * w1.x; u8[5] += wad * w1.y; u8[6] += wad * w1.z; u8[7] += wad * w1.w;
        }
        #pragma unroll
        for (int i = 0; i < 8; i++) red[wv * 512 + lane * 8 + i] = u8[i];
        __syncthreads();
        if (tid < 512) {
            float s = 0.f;
            #pragma unroll
            for (int w = 0; w < 16; w++) s += red[w * 512 + tid];
            uo[tid] = s;
        }
        __syncthreads();
        if (tid < 256) red[tid] = wa[tid] * bias[tid];
        __syncthreads();
        for (int o = 128; o >= 1; o >>= 1) {
            if (tid < o) red[tid] += red[tid + o];
            __syncthreads();
        }
        float off = red[0];

        const float4* u4 = (const float4*)uo;
        float4 ua = u4[lane * 2], ub = u4[lane * 2 + 1];
        for (int rr = 0; rr < 12; rr++) {
            int r = wv * 12 + rr;
            const float4* xr = (const float4*)(x + (size_t)(r * 2 + b) * 512);
            float4 a0 = xr[lane * 2], a1 = xr[lane * 2 + 1];
            float pp = a0.x*ua.x + a0.y*ua.y + a0.z*ua.z + a0.w*ua.w
                     + a1.x*ub.x + a1.y*ub.y + a1.z*ub.z + a1.w*ub.w;
            pp = wave_reduce_add(pp);
            if (lane == 0) ws[TO + tab * SS + r] = pp + off;
        }
        return;
    }

    // ---- C tables (verified body)
    {
        int m = blk - 200;                     // 0..3
        float4 wa4 = ((const float4*)(Wa + 512))[lane];
        for (int rr = 0; rr < 12; rr++) {
            int i = wv * 12 + rr;
            const float4* er = (const float4*)(entity
                + (size_t)(i * 2 + (m >> 1)) * 512 + (m & 1) * 256);
            float4 e4 = er[lane];
            float pp = e4.x*wa4.x + e4.y*wa4.y + e4.z*wa4.z + e4.w*wa4.w;
            pp = wave_reduce_add(pp);
            if (lane == 0) ws[TO + (8 + m) * SS + i] = pp;
        }
    }
}

// ===== K3: attention + output fc. 96 blocks (b, tg) x 1024 thr.
__global__ __launch_bounds__(1024) void k_attnout(
    const float* __restrict__ ba_p, const float* __restrict__ Wo,
    const float* __restrict__ bo, const float* __restrict__ ws,
    float* __restrict__ out)
{
    __shared__ float sp[8][SS];                       // 6 KB  [h*4+ti][s]
    __shared__ __align__(16) float2 part2[2048];      // 16 KB [(h*4+sq)*4+ti][d2:128]
    __shared__ __align__(16) float rows[4][512];      // 8 KB
    __shared__ float sout[2048];                      // 8 KB  [ti*512+c]
    int blk = blockIdx.x;
    int b   = blk / 48;
    int tg  = blk % 48;                    // t = tg*4 + ti
    int tid  = threadIdx.x;
    int wvi  = __builtin_amdgcn_readfirstlane(tid >> 6);
    int lane = tid & 63;
    const float* T = ws + TO;
    float ba = ba_p[0];

    // --- softmax: waves 0..7 own (h = wv>>2, ti = wv&3)   [verified r7 body]
    if (wvi < 8) {
        int h = wvi >> 2, ti = wvi & 3;
        int bh = 2 * b + h;
        int i_idx = bh * 48 + tg;
        float sc[3]; float mx = -1e30f;
        #pragma unroll
        for (int i = 0; i < 3; i++) {
            int s_ = lane + 64 * i;
            int m  = s_ & 3;
            int j  = ti * 48 + (s_ >> 2);
            float xv = T[m * SS + i_idx] + T[(4 + ti) * SS + s_]
                     + T[(8 + m) * SS + i_idx] - T[(8 + m) * SS + j] + ba;
            xv = (xv >= 0.f) ? xv : 0.01f * xv;      // leaky_relu
            sc[i] = xv; mx = fmaxf(mx, xv);
        }
        #pragma unroll
        for (int o = 32; o >= 1; o >>= 1) mx = fmaxf(mx, __shfl_xor(mx, o, 64));
        float sum = 0.f;
        #pragma unroll
        for (int i = 0; i < 3; i++) { sc[i] = __expf(sc[i] - mx); sum += sc[i]; }
        sum = wave_reduce_add(sum);
        float inv = 1.f / sum;
        #pragma unroll
        for (int i = 0; i < 3; i++) sp[wvi][lane + 64 * i] = sc[i] * inv;
    }
    __syncthreads();

    // --- PV: thread (h = tid>>9, sq = (tid>>7)&3, d2 = tid&127), float2, split-s x4
    {
        int h  = __builtin_amdgcn_readfirstlane(tid >> 9);
        int sq = __builtin_amdgcn_readfirstlane((tid >> 7) & 3);
        int d2 = tid & 127;
        const float2* src2 = (const float2*)(ws + (h ? EO : VO));   // [384][128] f2
        float2 acc2[4];
        #pragma unroll
        for (int ti = 0; ti < 4; ti++) acc2[ti] = make_float2(0.f, 0.f);
        int s0 = sq * 48;
        #pragma unroll 16
        for (int s2 = 0; s2 < 48; s2++) {
            int s = s0 + s2;
            float2 v = src2[(size_t)(s * 2 + b) * 128 + d2];
            #pragma unroll
            for (int ti = 0; ti < 4; ti++) {
                float p = sp[h * 4 + ti][s];
                acc2[ti].x += p * v.x;
                acc2[ti].y += p * v.y;
            }
        }
        #pragma unroll
        for (int ti = 0; ti < 4; ti++)
            part2[((h * 4 + sq) * 4 + ti) * 128 + d2] = acc2[ti];
    }
    __syncthreads();

    // --- reduce partials -> rows[ti][h*256+d]
    {
        const float* partf = (const float*)part2;    // [(h*4+sq)*4+ti][256]
        int ti = tid >> 8, dd = tid & 255;
        float r0 = 0.f, r1 = 0.f;
        #pragma unroll
        for (int sq = 0; sq < 4; sq++) {
            r0 += partf[((0 + sq) * 4 + ti) * 256 + dd];
            r1 += partf[((4 + sq) * 4 + ti) * 256 + dd];
        }
        rows[ti][dd]       = r0;
        rows[ti][256 + dd] = r1;
    }
    __syncthreads();

    // --- out GEMV: wave wv owns 32 cols; lane->k (8 floats); shfl reduce
    {
        const float4* rows4 = (const float4*)rows;   // [4][128]
        float4 rr[4][2];
        #pragma unroll
        for (int ti = 0; ti < 4; ti++) {
            rr[ti][0] = rows4[ti * 128 + lane * 2];
            rr[ti][1] = rows4[ti * 128 + lane * 2 + 1];
        }
        const float4* Wo4 = (const float4*)Wo;       // [512][128]
        int c0 = wvi * 32;
        #pragma unroll 4
        for (int i = 0; i < 32; i++) {
            int c = c0 + i;
            float4 w0 = Wo4[(size_t)c * 128 + lane * 2];
            float4 w1 = Wo4[(size_t)c * 128 + lane * 2 + 1];
            float pt[4];
            #pragma unroll
            for (int ti = 0; ti < 4; ti++) {
                pt[ti] = rr[ti][0].x * w0.x + rr[ti][0].y * w0.y
                       + rr[ti][0].z * w0.z + rr[ti][0].w * w0.w
                       + rr[ti][1].x * w1.x + rr[ti][1].y * w1.y
                       + rr[ti][1].z * w1.z + rr[ti][1].w * w1.w;
            }
            #pragma unroll
            for (int o = 32; o >= 1; o >>= 1) {
                #pragma unroll
                for (int ti = 0; ti < 4; ti++) pt[ti] += __shfl_xor(pt[ti], o, 64);
            }
            if (lane == 0) {
                #pragma unroll
                for (int ti = 0; ti < 4; ti++) sout[ti * 512 + c] = pt[ti];
            }
        }
    }
    __syncthreads();

    // --- coalesced store: 2048 outputs, 2 per thread
    #pragma unroll
    for (int o = 0; o < 2; o++) {
        int idx = tid + o * 1024;
        int ti = idx >> 9, c = idx & 511;
        int t = tg * 4 + ti;
        out[(size_t)(2 * t + b) * 512 + c] = sout[idx] + bo[c];
    }
}

extern "C" void kernel_launch(void* const* d_in, const int* in_sizes, int n_in,
                              void* d_out, int out_size, void* d_ws, size_t ws_size,
                              hipStream_t stream) {
    const float* query  = (const float*)d_in[0];
    const float* entity = (const float*)d_in[1];
    // d_in[2] ex_entity, d_in[3] ex_relation: dead
    const float* Wq = (const float*)d_in[4];  const float* bq = (const float*)d_in[5];
    const float* Wk = (const float*)d_in[6];  const float* bk = (const float*)d_in[7];
    const float* Wv = (const float*)d_in[8];  const float* bv = (const float*)d_in[9];
    const float* We = (const float*)d_in[10]; const float* be = (const float*)d_in[11];
    // d_in[12..15] dead
    const float* Wa = (const float*)d_in[16]; const float* ba = (const float*)d_in[17];
    const float* Wo = (const float*)d_in[18]; const float* bo = (const float*)d_in[19];
    float* ws  = (float*)d_ws;
    float* out = (float*)d_out;

    hipLaunchKernelGGL(k_trans,   dim3(64),  dim3(1024), 0, stream, Wv, We, ws);
    hipLaunchKernelGGL(k_projtab, dim3(204), dim3(1024), 0, stream,
                       query, entity, Wq, bq, Wk, bk, bv, We, be, Wa, ws);
    hipLaunchKernelGGL(k_attnout, dim3(96),  dim3(1024), 0, stream,
                       ba, Wo, bo, ws, out);
}